// Round 2
// baseline (391.471 us; speedup 1.0000x reference)
//
#include <hip/hip_runtime.h>
#include <hip/hip_cooperative_groups.h>
#include <math.h>

namespace cg = cooperative_groups;

#define NSLICE 64
#define DVEC   131072          // float4 per slice (524288 floats / 4)
#define NB     32              // chunks per slice
#define CHUNK4 (DVEC / NB)     // 4096 float4 per chunk (64 KiB)
#define TPB    256
#define NBLK   1024            // 4 blocks/CU with 256 thr -> 16 waves/CU, coop-safe
#define NTASK  (NSLICE * NB)   // 2048 tasks; each block does exactly 2 per phase

__inline__ __device__ float wave_reduce(float v) {
    #pragma unroll
    for (int off = 32; off > 0; off >>= 1) v += __shfl_down(v, off, 64);
    return v;
}

__global__ __launch_bounds__(TPB, 4) void fused_kernel(
        const float* __restrict__ q, const float* __restrict__ ent,
        float* __restrict__ pS, float* __restrict__ pC,
        float* __restrict__ out) {
    cg::grid_group grid = cg::this_grid();
    __shared__ float s_s[TPB / 64];
    __shared__ float s_c[TPB / 64];

    // ---- Phase 1: per-(slice,chunk) partial dots, no atomics ----
    for (int task = blockIdx.x; task < NTASK; task += NBLK) {
        const int i = task >> 5;        // slice
        const int j = task & 31;        // chunk
        const bool has_next = (i < NSLICE - 1);
        const float4* qi = (const float4*)q + (size_t)i * DVEC + (size_t)j * CHUNK4;
        const float4* qn = qi + DVEC;   // same chunk of slice i+1

        float self = 0.f, cross = 0.f;
        for (int t = threadIdx.x; t < CHUNK4; t += TPB) {
            float4 a = qi[t];
            self += a.x*a.x + a.y*a.y + a.z*a.z + a.w*a.w;
            if (has_next) {
                float4 b = qn[t];
                cross += a.x*b.x + a.y*b.y + a.z*b.z + a.w*b.w;
            }
        }
        const float sw = wave_reduce(self);
        const float cw = wave_reduce(cross);
        const int lane = threadIdx.x & 63;
        const int wid  = threadIdx.x >> 6;
        if (lane == 0) { s_s[wid] = sw; s_c[wid] = cw; }
        __syncthreads();
        if (threadIdx.x == 0) {
            pS[task] = s_s[0] + s_s[1] + s_s[2] + s_s[3];
            pC[task] = s_c[0] + s_c[1] + s_c[2] + s_c[3];
        }
        __syncthreads();   // protect LDS reuse on next grid-stride iteration
    }

    __threadfence();
    grid.sync();

    // ---- Phase 2+3: weights (redundant per block, broadcast loads) + combine ----
    for (int task = blockIdx.x; task < NTASK; task += NBLK) {
        const int i = task >> 5;
        const int j = task & 31;

        // reduce the 32 partials each for norms[i], adj[i-1], adj[i]
        float ni = 0.f, alo = 0.f, ahi = 0.f;
        #pragma unroll 8
        for (int t = 0; t < NB; t++) ni += pS[i * NB + t];
        if (i > 0) {
            #pragma unroll 8
            for (int t = 0; t < NB; t++) alo += pC[(i - 1) * NB + t];
        }
        if (i < NSLICE - 1) {
            #pragma unroll 8
            for (int t = 0; t < NB; t++) ahi += pC[i * NB + t];
        }

        // exact branch ladder (same priority + boundary rules as reference)
        const float ei = ent[i];
        int k1, k2;
        if (i == 0) {
            const int b0 = (ei >= ent[1]) ? 1 : 0;
            k1 = b0; k2 = b0;
        } else if (i == NSLICE - 1) {
            const int bL = (ei >= ent[NSLICE - 2]) ? (NSLICE - 2) : (NSLICE - 1);
            k1 = bL; k2 = bL;
        } else {
            const float ep = ent[i - 1], en = ent[i + 1];
            const bool ge_next = (ei >= en), ge_prev = (ei >= ep);
            const bool le_next = (ei <= en), le_prev = (ei <= ep);
            if      (ge_next && ge_prev) { k1 = i - 1; k2 = i + 1; }
            else if (le_next && ge_prev) { k1 = i - 1; k2 = i;     }
            else if (ge_next && le_prev) { k1 = i;     k2 = i + 1; }
            else                         { k1 = i;     k2 = i;     }
        }

        const float s_scale = 1.0f / sqrtf(524288.0f);
        const float s1 = ((k1 < i) ? alo : (k1 > i) ? ahi : ni) * s_scale;
        const float s2 = ((k2 < i) ? alo : (k2 > i) ? ahi : ni) * s_scale;
        const float m  = fmaxf(s1, s2);
        const float e1 = expf(s1 - m), e2 = expf(s2 - m);
        const float inv = 1.0f / (e1 + e2);
        const float wa = e1 * inv;
        const float wb = e2 * inv;

        const float4* qa = (const float4*)q + (size_t)k1 * DVEC + (size_t)j * CHUNK4;
        const float4* qb = (const float4*)q + (size_t)k2 * DVEC + (size_t)j * CHUNK4;
        float4* o = (float4*)out + (size_t)i * DVEC + (size_t)j * CHUNK4;
        for (int t = threadIdx.x; t < CHUNK4; t += TPB) {
            float4 x = qa[t];
            float4 y = qb[t];
            float4 r;
            r.x = wa * x.x + wb * y.x;
            r.y = wa * x.y + wb * y.y;
            r.z = wa * x.z + wb * y.z;
            r.w = wa * x.w + wb * y.w;
            o[t] = r;
        }
    }
}

extern "C" void kernel_launch(void* const* d_in, const int* in_sizes, int n_in,
                              void* d_out, int out_size, void* d_ws, size_t ws_size,
                              hipStream_t stream) {
    const float* c5d = (const float*)d_in[0];
    const float* ent = (const float*)d_in[1];
    float* out = (float*)d_out;

    // workspace: pS[2048] | pC[2048]  (fully written in phase 1 before any read)
    float* pS = (float*)d_ws;
    float* pC = pS + NTASK;

    void* args[] = {(void*)&c5d, (void*)&ent, (void*)&pS, (void*)&pC, (void*)&out};
    hipLaunchCooperativeKernel((void*)fused_kernel, dim3(NBLK), dim3(TPB),
                               args, 0, stream);
}

// Round 3
// 243.818 us; speedup vs baseline: 1.6056x; 1.6056x over previous
//
#include <hip/hip_runtime.h>
#include <math.h>

#define NSLICE 64
#define DVEC   131072          // float4 per slice (524288 floats / 4)
#define NB     32              // chunks per slice
#define CHUNK4 (DVEC / NB)     // 4096 float4 per chunk (64 KiB)
#define TPB    256
#define ITER   (CHUNK4 / TPB)  // 16 float4 per thread per stream
#define NTASK  (NSLICE * NB)   // 2048 blocks

__inline__ __device__ float wave_reduce(float v) {
    #pragma unroll
    for (int off = 32; off > 0; off >>= 1) v += __shfl_down(v, off, 64);
    return v;
}

// Kernel A: per-(slice,chunk) partials: pS[task]=partial dot(q[i],q[i]),
// pC[task]=partial dot(q[i],q[i+1]). Non-atomic, every slot written.
__global__ __launch_bounds__(TPB) void dots_kernel(
        const float4* __restrict__ q, float* __restrict__ pS, float* __restrict__ pC) {
    const int task = blockIdx.x;
    const int i = task >> 5;
    const int j = task & 31;
    const float4* qi = q + (size_t)i * DVEC + (size_t)j * CHUNK4 + threadIdx.x;

    float self = 0.f, cross = 0.f;
    if (i < NSLICE - 1) {
        const float4* qn = qi + DVEC;
        float s0=0.f,s1=0.f,s2=0.f,s3=0.f, c0=0.f,c1=0.f,c2=0.f,c3=0.f;
        #pragma unroll
        for (int t = 0; t < ITER; t += 4) {
            float4 a0 = qi[(t+0)*TPB]; float4 a1 = qi[(t+1)*TPB];
            float4 a2 = qi[(t+2)*TPB]; float4 a3 = qi[(t+3)*TPB];
            float4 b0 = qn[(t+0)*TPB]; float4 b1 = qn[(t+1)*TPB];
            float4 b2 = qn[(t+2)*TPB]; float4 b3 = qn[(t+3)*TPB];
            s0 += a0.x*a0.x + a0.y*a0.y + a0.z*a0.z + a0.w*a0.w;
            s1 += a1.x*a1.x + a1.y*a1.y + a1.z*a1.z + a1.w*a1.w;
            s2 += a2.x*a2.x + a2.y*a2.y + a2.z*a2.z + a2.w*a2.w;
            s3 += a3.x*a3.x + a3.y*a3.y + a3.z*a3.z + a3.w*a3.w;
            c0 += a0.x*b0.x + a0.y*b0.y + a0.z*b0.z + a0.w*b0.w;
            c1 += a1.x*b1.x + a1.y*b1.y + a1.z*b1.z + a1.w*b1.w;
            c2 += a2.x*b2.x + a2.y*b2.y + a2.z*b2.z + a2.w*b2.w;
            c3 += a3.x*b3.x + a3.y*b3.y + a3.z*b3.z + a3.w*b3.w;
        }
        self  = (s0 + s1) + (s2 + s3);
        cross = (c0 + c1) + (c2 + c3);
    } else {
        float s0=0.f,s1=0.f,s2=0.f,s3=0.f;
        #pragma unroll
        for (int t = 0; t < ITER; t += 4) {
            float4 a0 = qi[(t+0)*TPB]; float4 a1 = qi[(t+1)*TPB];
            float4 a2 = qi[(t+2)*TPB]; float4 a3 = qi[(t+3)*TPB];
            s0 += a0.x*a0.x + a0.y*a0.y + a0.z*a0.z + a0.w*a0.w;
            s1 += a1.x*a1.x + a1.y*a1.y + a1.z*a1.z + a1.w*a1.w;
            s2 += a2.x*a2.x + a2.y*a2.y + a2.z*a2.z + a2.w*a2.w;
            s3 += a3.x*a3.x + a3.y*a3.y + a3.z*a3.z + a3.w*a3.w;
        }
        self = (s0 + s1) + (s2 + s3);
    }

    __shared__ float r_s[TPB / 64];
    __shared__ float r_c[TPB / 64];
    const float sw = wave_reduce(self);
    const float cw = wave_reduce(cross);
    const int lane = threadIdx.x & 63;
    const int wid  = threadIdx.x >> 6;
    if (lane == 0) { r_s[wid] = sw; r_c[wid] = cw; }
    __syncthreads();
    if (threadIdx.x == 0) {
        pS[task] = r_s[0] + r_s[1] + r_s[2] + r_s[3];
        pC[task] = r_c[0] + r_c[1] + r_c[2] + r_c[3];
    }
}

// Kernel B: per-block weight computation (partials staged through LDS) +
// weighted combine: out[i] = w1*q[k1] + w2*q[k2].
__global__ __launch_bounds__(TPB) void combine_kernel(
        const float4* __restrict__ q, const float* __restrict__ ent,
        const float* __restrict__ pS, const float* __restrict__ pC,
        float4* __restrict__ out) {
    const int task = blockIdx.x;
    const int i = task >> 5;
    const int j = task & 31;
    const int tid = threadIdx.x;

    // stage the 96 relevant partials: [0:32)=pS[i], [32:64)=pC[i-1], [64:96)=pC[i]
    __shared__ float sp[96];
    if (tid < 32)      sp[tid] = pS[i * NB + tid];
    else if (tid < 64) sp[tid] = (i > 0)          ? pC[(i - 1) * NB + (tid - 32)] : 0.f;
    else if (tid < 96) sp[tid] = (i < NSLICE - 1) ? pC[i * NB + (tid - 64)]       : 0.f;
    __syncthreads();

    float ni = 0.f, alo = 0.f, ahi = 0.f;
    #pragma unroll
    for (int t = 0; t < NB; t++) {      // LDS same-address broadcast: conflict-free
        ni  += sp[t];
        alo += sp[32 + t];
        ahi += sp[64 + t];
    }

    // exact branch ladder (same priority + boundary rules as the reference)
    const float ei = ent[i];
    int k1, k2;
    if (i == 0) {
        const int b0 = (ei >= ent[1]) ? 1 : 0;
        k1 = b0; k2 = b0;
    } else if (i == NSLICE - 1) {
        const int bL = (ei >= ent[NSLICE - 2]) ? (NSLICE - 2) : (NSLICE - 1);
        k1 = bL; k2 = bL;
    } else {
        const float ep = ent[i - 1], en = ent[i + 1];
        const bool ge_next = (ei >= en), ge_prev = (ei >= ep);
        const bool le_next = (ei <= en), le_prev = (ei <= ep);
        if      (ge_next && ge_prev) { k1 = i - 1; k2 = i + 1; }
        else if (le_next && ge_prev) { k1 = i - 1; k2 = i;     }
        else if (ge_next && le_prev) { k1 = i;     k2 = i + 1; }
        else                         { k1 = i;     k2 = i;     }
    }

    const float s_scale = 1.0f / sqrtf(524288.0f);
    const float s1 = ((k1 < i) ? alo : (k1 > i) ? ahi : ni) * s_scale;
    const float s2 = ((k2 < i) ? alo : (k2 > i) ? ahi : ni) * s_scale;
    const float m  = fmaxf(s1, s2);
    const float e1 = expf(s1 - m), e2 = expf(s2 - m);
    const float inv = 1.0f / (e1 + e2);
    const float wa = e1 * inv;
    const float wb = e2 * inv;

    const float4* qa = q + (size_t)k1 * DVEC + (size_t)j * CHUNK4 + tid;
    const float4* qb = q + (size_t)k2 * DVEC + (size_t)j * CHUNK4 + tid;
    float4* o = out + (size_t)i * DVEC + (size_t)j * CHUNK4 + tid;
    #pragma unroll
    for (int t = 0; t < ITER; t += 4) {
        float4 x0 = qa[(t+0)*TPB]; float4 x1 = qa[(t+1)*TPB];
        float4 x2 = qa[(t+2)*TPB]; float4 x3 = qa[(t+3)*TPB];
        float4 y0 = qb[(t+0)*TPB]; float4 y1 = qb[(t+1)*TPB];
        float4 y2 = qb[(t+2)*TPB]; float4 y3 = qb[(t+3)*TPB];
        float4 r0, r1, r2, r3;
        r0.x = wa*x0.x + wb*y0.x; r0.y = wa*x0.y + wb*y0.y;
        r0.z = wa*x0.z + wb*y0.z; r0.w = wa*x0.w + wb*y0.w;
        r1.x = wa*x1.x + wb*y1.x; r1.y = wa*x1.y + wb*y1.y;
        r1.z = wa*x1.z + wb*y1.z; r1.w = wa*x1.w + wb*y1.w;
        r2.x = wa*x2.x + wb*y2.x; r2.y = wa*x2.y + wb*y2.y;
        r2.z = wa*x2.z + wb*y2.z; r2.w = wa*x2.w + wb*y2.w;
        r3.x = wa*x3.x + wb*y3.x; r3.y = wa*x3.y + wb*y3.y;
        r3.z = wa*x3.z + wb*y3.z; r3.w = wa*x3.w + wb*y3.w;
        o[(t+0)*TPB] = r0; o[(t+1)*TPB] = r1;
        o[(t+2)*TPB] = r2; o[(t+3)*TPB] = r3;
    }
}

extern "C" void kernel_launch(void* const* d_in, const int* in_sizes, int n_in,
                              void* d_out, int out_size, void* d_ws, size_t ws_size,
                              hipStream_t stream) {
    const float4* c5d = (const float4*)d_in[0];
    const float*  ent = (const float*)d_in[1];
    float4* out = (float4*)d_out;

    // workspace: pS[2048] | pC[2048] — every slot written by dots_kernel, no memset
    float* pS = (float*)d_ws;
    float* pC = pS + NTASK;

    dots_kernel<<<NTASK, TPB, 0, stream>>>(c5d, pS, pC);
    combine_kernel<<<NTASK, TPB, 0, stream>>>(c5d, ent, pS, pC, out);
}